// Round 5
// baseline (143.851 us; speedup 1.0000x reference)
//
#include <hip/hip_runtime.h>
#include <hip/hip_bf16.h>

#define N_NODES 50000
#define N_EDGES 600000
#define BN_EPS 1e-5f
#define ELL_MAX 64          // per-node list cap; P(deg>=64) ~ 1e-30
#define N_BUCKETS 782       // ceil(50000/64) 64-node tiles
#define NSUB 32             // sub-buckets per bucket (atomic contention shard)
#define SUBCAP 64           // per sub-bucket capacity; lambda=24, +8.2 sigma

typedef short bf16x8 __attribute__((ext_vector_type(8)));
typedef float f32x4 __attribute__((ext_vector_type(4)));

__device__ __forceinline__ ushort f2bf(float f) {
    unsigned u = __float_as_uint(f);
    u += 0x7fffu + ((u >> 16) & 1u);
    return (ushort)(u >> 16);
}
__device__ __forceinline__ float bf_lo(unsigned u) { return __uint_as_float(u << 16); }
__device__ __forceinline__ float bf_hi(unsigned u) { return __uint_as_float(u & 0xffff0000u); }

// ===========================================================================
// prep_scatter: [x->bf16 | edge binning | weight transpose | bn fold].
// Conv range FIRST so edge-atomic arrivals are staggered by retiring conv
// blocks. Bucket entry: (src << 6) | (dst & 63), at bucket[b][sub=blk&31][p].
// ===========================================================================
#define T_CONV  (N_NODES * 32)                 // 1,600,000
#define T_EDGE  N_EDGES                        // 600,000
#define T_W     (128 * 256 + 128 * 128)        // 49,152
#define T_BN    128
#define T_TOTAL (T_CONV + T_EDGE + T_W + T_BN)

__global__ __launch_bounds__(256) void prep_scatter_kernel(
    const float* __restrict__ x, const int* __restrict__ eidx,
    const float* __restrict__ W1l, const float* __restrict__ W1r,
    const float* __restrict__ W2l, const float* __restrict__ W2r,
    const float* __restrict__ gamma, const float* __restrict__ beta,
    const float* __restrict__ mean, const float* __restrict__ var,
    const float* __restrict__ b1,
    ushort* __restrict__ Xb, ushort* __restrict__ W1T, ushort* __restrict__ W2T2,
    float* __restrict__ scale_, float* __restrict__ shift_,
    int* __restrict__ bcnt, unsigned* __restrict__ bucket) {
    int t = blockIdx.x * 256 + threadIdx.x;
    if (t < T_CONV) {
        int row = t >> 5, c4 = t & 31;
        float4 v = *(const float4*)(x + (size_t)row * 128 + c4 * 4);
        ushort4 o;
        o.x = f2bf(v.x); o.y = f2bf(v.y); o.z = f2bf(v.z); o.w = f2bf(v.w);
        *(ushort4*)(Xb + (size_t)row * 128 + c4 * 4) = o;
    } else if (t < T_CONV + T_EDGE) {
        int e = t - T_CONV;
        int src = eidx[e];
        int dst = eidx[N_EDGES + e];
        int b = dst >> 6;
        int sub = blockIdx.x & (NSUB - 1);
        int p = atomicAdd(&bcnt[(b << 5) + sub], 1);
        if (p < SUBCAP)
            bucket[((size_t)b << 11) + (sub << 6) + p] =
                ((unsigned)src << 6) | (unsigned)(dst & 63);
    } else if (t < T_CONV + T_EDGE + T_W) {
        int t2 = t - (T_CONV + T_EDGE);
        if (t2 < 128 * 256) {
            int c = t2 >> 8, k = t2 & 255;
            float v = (k < 128) ? W1l[k * 128 + c] : W1r[(k - 128) * 128 + c];
            W1T[c * 256 + k] = f2bf(v);
        } else {
            int t3 = t2 - 128 * 256;            // 0..16383
            int c = t3 >> 7, k = t3 & 127;
            float v = (c < 64) ? W2l[k * 64 + c] : W2r[k * 64 + (c - 64)];
            W2T2[c * 128 + k] = f2bf(v);
        }
    } else if (t < T_TOTAL) {
        int c = t - (T_CONV + T_EDGE + T_W);
        float sc = gamma[c] * rsqrtf(var[c] + BN_EPS);
        scale_[c] = sc;
        shift_[c] = sc * (b1[c] - mean[c]) + beta[c];
    }
}

// ===========================================================================
// build_ell: one block per bucket. 32 sub-buckets -> LDS per-node lists ->
// coalesced global ell[node][64] (ushort) + deg[node]. ~8KB in + 8KB out
// per block; pays the list-build cost ONCE (fused1/finish just read).
// ===========================================================================
__global__ __launch_bounds__(256) void build_ell_kernel(
    const unsigned* __restrict__ bucket, const int* __restrict__ bcnt,
    ushort* __restrict__ ell, int* __restrict__ deg) {
    __shared__ ushort lell[64 * ELL_MAX];   // 8 KB
    __shared__ int lcnt[64];
    __shared__ int scnt[NSUB];
    const int tid = threadIdx.x;
    const int bkt = blockIdx.x;
    const int row0 = bkt << 6;

    if (tid < 64) lcnt[tid] = 0;
    else if (tid < 64 + NSUB) {
        int v = bcnt[(bkt << 5) + (tid - 64)];
        scnt[tid - 64] = v > SUBCAP ? SUBCAP : v;
    }
    __syncthreads();
    for (int i = tid; i < NSUB * SUBCAP; i += 256) {
        int s = i >> 6, q = i & 63;
        if (q < scnt[s]) {
            unsigned u = bucket[((size_t)bkt << 11) + i];
            int dl = u & 63;
            int p = atomicAdd(&lcnt[dl], 1);
            if (p < ELL_MAX) lell[(dl << 6) + p] = (ushort)(u >> 6);
        }
    }
    __syncthreads();
    if (tid < 64) {
        int node = row0 + tid;
        if (node < N_NODES) deg[node] = lcnt[tid];
    }
    // 8KB list block -> global, coalesced uint4 (garbage beyond capped length
    // is never read: consumers stop at min(deg,64)).
    const uint4* srcp = (const uint4*)lell;
    uint4* dstp = (uint4*)(ell + ((size_t)row0 << 6));
    #pragma unroll
    for (int i = 0; i < 2; ++i) dstp[i * 256 + tid] = srcp[i * 256 + tid];
}

// ===========================================================================
// fused1 (512 threads = 8 waves; one 64-row tile per block; LDS 32KB ->
// 4-blocks/CU headroom, grid-capped at ~3/CU = 24 waves):
//   A1: self rows Xb -> sA granules 16..31
//   A2: gather-mean from Xb via global ell/deg -> sA granules 0..15
//       (wave w owns rows [8w,8w+8): 4 nodes x 2 kq; 8 loads in flight/lane)
//   B : MFMA1  H = relu(bn([agg|self] @ W1T^T))
//   C : H -> sH (low 16KB of sA, swizzled)
//   D : MFMA2  [Q|R] = H @ W2T2^T ; Q bf16, R fp32 (+b2)
// ===========================================================================
__global__ __launch_bounds__(512) void fused1_kernel(
    const ushort* __restrict__ Xb, const ushort* __restrict__ ell,
    const int* __restrict__ deg,
    const ushort* __restrict__ W1T, const ushort* __restrict__ W2T2,
    const float* __restrict__ scale_, const float* __restrict__ shift_,
    const float* __restrict__ b2,
    ushort* __restrict__ Q, float* __restrict__ R) {
    __shared__ unsigned sAd[64 * 32 * 4];   // 32 KB
    const int tid = threadIdx.x;
    const int bkt = blockIdx.x;
    const int row0 = bkt << 6;

    // ---- A1: self-stage, 1024 granules over 512 threads ----
    #pragma unroll
    for (int i = 0; i < 2; ++i) {
        int g = i * 512 + tid;
        int r = g >> 4, gs = g & 15;
        int row = row0 + r;
        uint4 v = make_uint4(0, 0, 0, 0);
        if (row < N_NODES) v = *(const uint4*)(Xb + ((size_t)row << 7) + gs * 8);
        *(uint4*)&sAd[((r << 5) + ((16 + gs) ^ (r & 7))) << 2] = v;
    }

    // ---- A2: gather-mean, 8 waves x (4 nodes x 2 kq), lane = 8-ch granule --
    const int w = tid >> 6, l = tid & 63;
    const int grp = l >> 4, lane16 = l & 15;
    for (int kq = 0; kq < 2; ++kq) {
        const int r = (w << 3) + (kq << 2) + grp;   // 0..63
        const int node = row0 + r;
        const int dg = (node < N_NODES) ? deg[node] : 0;
        const int end = dg < ELL_MAX ? dg : ELL_MAX;
        const ushort* Lp = ell + ((size_t)node << 6);
        float a0 = 0.f, a1 = 0.f, a2 = 0.f, a3 = 0.f;
        float a4 = 0.f, a5 = 0.f, a6 = 0.f, a7 = 0.f;
        int j = 0;
        for (; j + 8 <= end; j += 8) {
            ushort4 sa = *(const ushort4*)(Lp + j);
            ushort4 sb = *(const ushort4*)(Lp + j + 4);
            uint4 u0 = *(const uint4*)(Xb + ((size_t)sa.x << 7) + lane16 * 8);
            uint4 u1 = *(const uint4*)(Xb + ((size_t)sa.y << 7) + lane16 * 8);
            uint4 u2 = *(const uint4*)(Xb + ((size_t)sa.z << 7) + lane16 * 8);
            uint4 u3 = *(const uint4*)(Xb + ((size_t)sa.w << 7) + lane16 * 8);
            uint4 u4 = *(const uint4*)(Xb + ((size_t)sb.x << 7) + lane16 * 8);
            uint4 u5 = *(const uint4*)(Xb + ((size_t)sb.y << 7) + lane16 * 8);
            uint4 u6 = *(const uint4*)(Xb + ((size_t)sb.z << 7) + lane16 * 8);
            uint4 u7 = *(const uint4*)(Xb + ((size_t)sb.w << 7) + lane16 * 8);
            a0 += bf_lo(u0.x) + bf_lo(u1.x) + bf_lo(u2.x) + bf_lo(u3.x)
                + bf_lo(u4.x) + bf_lo(u5.x) + bf_lo(u6.x) + bf_lo(u7.x);
            a1 += bf_hi(u0.x) + bf_hi(u1.x) + bf_hi(u2.x) + bf_hi(u3.x)
                + bf_hi(u4.x) + bf_hi(u5.x) + bf_hi(u6.x) + bf_hi(u7.x);
            a2 += bf_lo(u0.y) + bf_lo(u1.y) + bf_lo(u2.y) + bf_lo(u3.y)
                + bf_lo(u4.y) + bf_lo(u5.y) + bf_lo(u6.y) + bf_lo(u7.y);
            a3 += bf_hi(u0.y) + bf_hi(u1.y) + bf_hi(u2.y) + bf_hi(u3.y)
                + bf_hi(u4.y) + bf_hi(u5.y) + bf_hi(u6.y) + bf_hi(u7.y);
            a4 += bf_lo(u0.z) + bf_lo(u1.z) + bf_lo(u2.z) + bf_lo(u3.z)
                + bf_lo(u4.z) + bf_lo(u5.z) + bf_lo(u6.z) + bf_lo(u7.z);
            a5 += bf_hi(u0.z) + bf_hi(u1.z) + bf_hi(u2.z) + bf_hi(u3.z)
                + bf_hi(u4.z) + bf_hi(u5.z) + bf_hi(u6.z) + bf_hi(u7.z);
            a6 += bf_lo(u0.w) + bf_lo(u1.w) + bf_lo(u2.w) + bf_lo(u3.w)
                + bf_lo(u4.w) + bf_lo(u5.w) + bf_lo(u6.w) + bf_lo(u7.w);
            a7 += bf_hi(u0.w) + bf_hi(u1.w) + bf_hi(u2.w) + bf_hi(u3.w)
                + bf_hi(u4.w) + bf_hi(u5.w) + bf_hi(u6.w) + bf_hi(u7.w);
        }
        for (; j + 4 <= end; j += 4) {
            ushort4 sa = *(const ushort4*)(Lp + j);
            uint4 u0 = *(const uint4*)(Xb + ((size_t)sa.x << 7) + lane16 * 8);
            uint4 u1 = *(const uint4*)(Xb + ((size_t)sa.y << 7) + lane16 * 8);
            uint4 u2 = *(const uint4*)(Xb + ((size_t)sa.z << 7) + lane16 * 8);
            uint4 u3 = *(const uint4*)(Xb + ((size_t)sa.w << 7) + lane16 * 8);
            a0 += bf_lo(u0.x) + bf_lo(u1.x) + bf_lo(u2.x) + bf_lo(u3.x);
            a1 += bf_hi(u0.x) + bf_hi(u1.x) + bf_hi(u2.x) + bf_hi(u3.x);
            a2 += bf_lo(u0.y) + bf_lo(u1.y) + bf_lo(u2.y) + bf_lo(u3.y);
            a3 += bf_hi(u0.y) + bf_hi(u1.y) + bf_hi(u2.y) + bf_hi(u3.y);
            a4 += bf_lo(u0.z) + bf_lo(u1.z) + bf_lo(u2.z) + bf_lo(u3.z);
            a5 += bf_hi(u0.z) + bf_hi(u1.z) + bf_hi(u2.z) + bf_hi(u3.z);
            a6 += bf_lo(u0.w) + bf_lo(u1.w) + bf_lo(u2.w) + bf_lo(u3.w);
            a7 += bf_hi(u0.w) + bf_hi(u1.w) + bf_hi(u2.w) + bf_hi(u3.w);
        }
        for (; j < end; ++j) {
            int s = Lp[j];
            uint4 u = *(const uint4*)(Xb + ((size_t)s << 7) + lane16 * 8);
            a0 += bf_lo(u.x); a1 += bf_hi(u.x);
            a2 += bf_lo(u.y); a3 += bf_hi(u.y);
            a4 += bf_lo(u.z); a5 += bf_hi(u.z);
            a6 += bf_lo(u.w); a7 += bf_hi(u.w);
        }
        float ic = 1.0f / fmaxf((float)dg, 1.0f);
        uint4 o;
        o.x = (unsigned)f2bf(a0 * ic) | ((unsigned)f2bf(a1 * ic) << 16);
        o.y = (unsigned)f2bf(a2 * ic) | ((unsigned)f2bf(a3 * ic) << 16);
        o.z = (unsigned)f2bf(a4 * ic) | ((unsigned)f2bf(a5 * ic) << 16);
        o.w = (unsigned)f2bf(a6 * ic) | ((unsigned)f2bf(a7 * ic) << 16);
        *(uint4*)&sAd[((r << 5) + (lane16 ^ (r & 7))) << 2] = o;
    }
    __syncthreads();

    // ---- B: MFMA1 (8 waves: (w&3) row-tile x (w>>2) col-half, 4 tiles) ----
    const bf16x8* sA8 = (const bf16x8*)sAd;
    const int lr = l & 15, lk = l >> 4;
    const int wr = (w & 3) << 4;     // 0,16,32,48
    const int wc = (w >> 2) << 6;    // 0,64

    f32x4 acc1[4];
    #pragma unroll
    for (int ni = 0; ni < 4; ++ni) acc1[ni] = (f32x4){0.f, 0.f, 0.f, 0.f};

    #pragma unroll
    for (int kk = 0; kk < 8; ++kk) {
        int r = wr + lr;
        bf16x8 a = sA8[(r << 5) + ((kk * 4 + lk) ^ (r & 7))];
        #pragma unroll
        for (int ni = 0; ni < 4; ++ni) {
            int c = wc + ni * 16 + lr;
            bf16x8 b = *(const bf16x8*)(W1T + (size_t)c * 256 + kk * 32 + lk * 8);
            acc1[ni] = __builtin_amdgcn_mfma_f32_16x16x32_bf16(b, a, acc1[ni], 0, 0, 0);
        }
    }
    __syncthreads();   // all sA reads done before H overwrites low 16KB

    // ---- C: bn+relu, H (bf16) -> sH = sAd[0..16KB), [64 r][16 g] swizzled --
    #pragma unroll
    for (int ni = 0; ni < 4; ++ni) {
        int c0 = wc + ni * 16 + lk * 4;
        float4 sc = *(const float4*)(scale_ + c0);
        float4 sh = *(const float4*)(shift_ + c0);
        int g = c0 >> 3;
        int sub = (c0 & 4) ? 8 : 0;
        int r = wr + lr;
        float h0 = fmaxf(acc1[ni][0] * sc.x + sh.x, 0.f);
        float h1 = fmaxf(acc1[ni][1] * sc.y + sh.y, 0.f);
        float h2 = fmaxf(acc1[ni][2] * sc.z + sh.z, 0.f);
        float h3 = fmaxf(acc1[ni][3] * sc.w + sh.w, 0.f);
        uint2 o;
        o.x = (unsigned)f2bf(h0) | ((unsigned)f2bf(h1) << 16);
        o.y = (unsigned)f2bf(h2) | ((unsigned)f2bf(h3) << 16);
        *(uint2*)((char*)sAd + (((r << 4) + (g ^ (r & 7))) << 4) + sub) = o;
    }
    __syncthreads();

    // ---- D: MFMA2  [Q|R] = H @ W2T2^T ----
    f32x4 acc2[4];
    #pragma unroll
    for (int ni = 0; ni < 4; ++ni) acc2[ni] = (f32x4){0.f, 0.f, 0.f, 0.f};

    const int r2 = wr + lr;
    #pragma unroll
    for (int kk = 0; kk < 4; ++kk) {
        bf16x8 a = *(const bf16x8*)((const char*)sAd +
                                    (((r2 << 4) + ((kk * 4 + lk) ^ (r2 & 7))) << 4));
        #pragma unroll
        for (int ni = 0; ni < 4; ++ni) {
            int c = wc + ni * 16 + lr;
            bf16x8 b = *(const bf16x8*)(W2T2 + (size_t)c * 128 + kk * 32 + lk * 8);
            acc2[ni] = __builtin_amdgcn_mfma_f32_16x16x32_bf16(b, a, acc2[ni], 0, 0, 0);
        }
    }

    const int rowo = row0 + r2;
    if (rowo < N_NODES) {
        #pragma unroll
        for (int ni = 0; ni < 4; ++ni) {
            int cw = wc + ni * 16 + lk * 4;
            if (cw < 64) {
                ushort4 o;
                o.x = f2bf(acc2[ni][0]); o.y = f2bf(acc2[ni][1]);
                o.z = f2bf(acc2[ni][2]); o.w = f2bf(acc2[ni][3]);
                *(ushort4*)(Q + ((size_t)rowo << 6) + cw) = o;
            } else {
                int c0 = cw - 64;
                float4 bias = *(const float4*)(b2 + c0);
                float4 o;
                o.x = acc2[ni][0] + bias.x; o.y = acc2[ni][1] + bias.y;
                o.z = acc2[ni][2] + bias.z; o.w = acc2[ni][3] + bias.w;
                *(float4*)(R + ((size_t)rowo << 6) + c0) = o;
            }
        }
    }
}

// ===========================================================================
// finish: out[n] = mean_j Q[j] + R[n].  256 threads, 16 nodes/block, 3125
// blocks (12500 waves -> fully resident). Q is 6.4MB (L2/L3-hot).
// ===========================================================================
__global__ __launch_bounds__(256) void finish_kernel(
    const ushort* __restrict__ Q, const float* __restrict__ R,
    const ushort* __restrict__ ell, const int* __restrict__ deg,
    float* __restrict__ out) {
    const int tid = threadIdx.x;
    const int grp = tid >> 4, lane16 = tid & 15;
    const int node = blockIdx.x * 16 + grp;
    if (node >= N_NODES) return;
    const int dg = deg[node];
    const int end = dg < ELL_MAX ? dg : ELL_MAX;
    const ushort* Lp = ell + ((size_t)node << 6);
    float a0 = 0.f, a1 = 0.f, a2 = 0.f, a3 = 0.f;
    int j = 0;
    for (; j + 8 <= end; j += 8) {
        ushort4 sa = *(const ushort4*)(Lp + j);
        ushort4 sb = *(const ushort4*)(Lp + j + 4);
        uint2 u0 = *(const uint2*)(Q + ((size_t)sa.x << 6) + lane16 * 4);
        uint2 u1 = *(const uint2*)(Q + ((size_t)sa.y << 6) + lane16 * 4);
        uint2 u2 = *(const uint2*)(Q + ((size_t)sa.z << 6) + lane16 * 4);
        uint2 u3 = *(const uint2*)(Q + ((size_t)sa.w << 6) + lane16 * 4);
        uint2 u4 = *(const uint2*)(Q + ((size_t)sb.x << 6) + lane16 * 4);
        uint2 u5 = *(const uint2*)(Q + ((size_t)sb.y << 6) + lane16 * 4);
        uint2 u6 = *(const uint2*)(Q + ((size_t)sb.z << 6) + lane16 * 4);
        uint2 u7 = *(const uint2*)(Q + ((size_t)sb.w << 6) + lane16 * 4);
        a0 += bf_lo(u0.x) + bf_lo(u1.x) + bf_lo(u2.x) + bf_lo(u3.x)
            + bf_lo(u4.x) + bf_lo(u5.x) + bf_lo(u6.x) + bf_lo(u7.x);
        a1 += bf_hi(u0.x) + bf_hi(u1.x) + bf_hi(u2.x) + bf_hi(u3.x)
            + bf_hi(u4.x) + bf_hi(u5.x) + bf_hi(u6.x) + bf_hi(u7.x);
        a2 += bf_lo(u0.y) + bf_lo(u1.y) + bf_lo(u2.y) + bf_lo(u3.y)
            + bf_lo(u4.y) + bf_lo(u5.y) + bf_lo(u6.y) + bf_lo(u7.y);
        a3 += bf_hi(u0.y) + bf_hi(u1.y) + bf_hi(u2.y) + bf_hi(u3.y)
            + bf_hi(u4.y) + bf_hi(u5.y) + bf_hi(u6.y) + bf_hi(u7.y);
    }
    for (; j + 4 <= end; j += 4) {
        ushort4 ss = *(const ushort4*)(Lp + j);
        uint2 u0 = *(const uint2*)(Q + ((size_t)ss.x << 6) + lane16 * 4);
        uint2 u1 = *(const uint2*)(Q + ((size_t)ss.y << 6) + lane16 * 4);
        uint2 u2 = *(const uint2*)(Q + ((size_t)ss.z << 6) + lane16 * 4);
        uint2 u3 = *(const uint2*)(Q + ((size_t)ss.w << 6) + lane16 * 4);
        a0 += bf_lo(u0.x) + bf_lo(u1.x) + bf_lo(u2.x) + bf_lo(u3.x);
        a1 += bf_hi(u0.x) + bf_hi(u1.x) + bf_hi(u2.x) + bf_hi(u3.x);
        a2 += bf_lo(u0.y) + bf_lo(u1.y) + bf_lo(u2.y) + bf_lo(u3.y);
        a3 += bf_hi(u0.y) + bf_hi(u1.y) + bf_hi(u2.y) + bf_hi(u3.y);
    }
    for (; j < end; ++j) {
        int s = Lp[j];
        uint2 u = *(const uint2*)(Q + ((size_t)s << 6) + lane16 * 4);
        a0 += bf_lo(u.x); a1 += bf_hi(u.x);
        a2 += bf_lo(u.y); a3 += bf_hi(u.y);
    }
    float ic = 1.0f / fmaxf((float)dg, 1.0f);
    float4 r4 = *(const float4*)(R + ((size_t)node << 6) + lane16 * 4);
    float4 o;
    o.x = a0 * ic + r4.x;
    o.y = a1 * ic + r4.y;
    o.z = a2 * ic + r4.z;
    o.w = a3 * ic + r4.w;
    *(float4*)(out + ((size_t)node << 6) + lane16 * 4) = o;
}

// ---------------------------------------------------------------------------
extern "C" void kernel_launch(void* const* d_in, const int* in_sizes, int n_in,
                              void* d_out, int out_size, void* d_ws, size_t ws_size,
                              hipStream_t stream) {
    const float* x     = (const float*)d_in[0];
    const int*   eidx  = (const int*)d_in[1];
    const float* W1_l  = (const float*)d_in[2];
    const float* W1_r  = (const float*)d_in[3];
    const float* b1    = (const float*)d_in[4];
    const float* gamma = (const float*)d_in[5];
    const float* beta  = (const float*)d_in[6];
    const float* mean  = (const float*)d_in[7];
    const float* var   = (const float*)d_in[8];
    const float* W2_l  = (const float*)d_in[9];
    const float* W2_r  = (const float*)d_in[10];
    const float* b2    = (const float*)d_in[11];
    float* out = (float*)d_out;

    char* p = (char*)d_ws;
    ushort* Xb   = (ushort*)p; p += (size_t)N_NODES * 128 * 2;            // 12.8 MB
    ushort* Q    = (ushort*)p; p += (size_t)N_NODES * 64 * 2;             //  6.4 MB
    float*  R    = (float*)p;  p += (size_t)N_NODES * 64 * 4;             // 12.8 MB
    ushort* W1T  = (ushort*)p; p += 128 * 256 * 2;
    ushort* W2T2 = (ushort*)p; p += 128 * 128 * 2;
    float* scale_ = (float*)p; p += 128 * 4;
    float* shift_ = (float*)p; p += 128 * 4;
    unsigned* bucket = (unsigned*)p; p += (size_t)N_BUCKETS * NSUB * SUBCAP * 4; // 6.4 MB
    int* bcnt    = (int*)p;    p += (size_t)N_BUCKETS * NSUB * 4;         // 100 KB
    ushort* ell  = (ushort*)p; p += (size_t)N_BUCKETS * 64 * ELL_MAX * 2; //  6.4 MB
    int* deg     = (int*)p;    p += (size_t)N_NODES * 4;                  // 200 KB

    hipMemsetAsync(bcnt, 0, (size_t)N_BUCKETS * NSUB * sizeof(int), stream);

    prep_scatter_kernel<<<(T_TOTAL + 255) / 256, 256, 0, stream>>>(
        x, eidx, W1_l, W1_r, W2_l, W2_r, gamma, beta, mean, var, b1,
        Xb, W1T, W2T2, scale_, shift_, bcnt, bucket);

    build_ell_kernel<<<N_BUCKETS, 256, 0, stream>>>(bucket, bcnt, ell, deg);

    fused1_kernel<<<N_BUCKETS, 512, 0, stream>>>(
        Xb, ell, deg, W1T, W2T2, scale_, shift_, b2, Q, R);

    finish_kernel<<<(N_NODES + 15) / 16, 256, 0, stream>>>(Q, R, ell, deg, out);
}

// Round 6
// 133.842 us; speedup vs baseline: 1.0748x; 1.0748x over previous
//
#include <hip/hip_runtime.h>
#include <hip/hip_bf16.h>

#define N_NODES 50000
#define N_EDGES 600000
#define BN_EPS 1e-5f
#define ELL_MAX 64          // per-node list cap; P(deg>=64) ~ 1e-30
#define N_BUCKETS 782       // ceil(50000/64) 64-node tiles
#define NSUB 32             // sub-buckets per bucket (atomic contention shard)
#define SUBCAP 64           // per sub-bucket capacity; lambda=24, +8.2 sigma

typedef short bf16x8 __attribute__((ext_vector_type(8)));
typedef float f32x4 __attribute__((ext_vector_type(4)));

__device__ __forceinline__ ushort f2bf(float f) {
    unsigned u = __float_as_uint(f);
    u += 0x7fffu + ((u >> 16) & 1u);
    return (ushort)(u >> 16);
}
__device__ __forceinline__ float bf_lo(unsigned u) { return __uint_as_float(u << 16); }
__device__ __forceinline__ float bf_hi(unsigned u) { return __uint_as_float(u & 0xffff0000u); }

// ===========================================================================
// prep_scatter: [x->bf16 | edge binning | weight transpose | bn fold].
// Bucket entry: (src << 6) | (dst & 63), at bucket[b][sub=blk&31][p].
// ===========================================================================
#define T_CONV  (N_NODES * 32)                 // 1,600,000
#define T_EDGE  N_EDGES                        // 600,000
#define T_W     (128 * 256 + 128 * 128)        // 49,152
#define T_BN    128
#define T_TOTAL (T_CONV + T_EDGE + T_W + T_BN)

__global__ __launch_bounds__(256) void prep_scatter_kernel(
    const float* __restrict__ x, const int* __restrict__ eidx,
    const float* __restrict__ W1l, const float* __restrict__ W1r,
    const float* __restrict__ W2l, const float* __restrict__ W2r,
    const float* __restrict__ gamma, const float* __restrict__ beta,
    const float* __restrict__ mean, const float* __restrict__ var,
    const float* __restrict__ b1,
    ushort* __restrict__ Xb, ushort* __restrict__ W1T, ushort* __restrict__ W2T2,
    float* __restrict__ scale_, float* __restrict__ shift_,
    int* __restrict__ bcnt, unsigned* __restrict__ bucket) {
    int t = blockIdx.x * 256 + threadIdx.x;
    if (t < T_CONV) {
        int row = t >> 5, c4 = t & 31;
        float4 v = *(const float4*)(x + (size_t)row * 128 + c4 * 4);
        ushort4 o;
        o.x = f2bf(v.x); o.y = f2bf(v.y); o.z = f2bf(v.z); o.w = f2bf(v.w);
        *(ushort4*)(Xb + (size_t)row * 128 + c4 * 4) = o;
    } else if (t < T_CONV + T_EDGE) {
        int e = t - T_CONV;
        int src = eidx[e];
        int dst = eidx[N_EDGES + e];
        int b = dst >> 6;
        int sub = blockIdx.x & (NSUB - 1);
        int p = atomicAdd(&bcnt[(b << 5) + sub], 1);
        if (p < SUBCAP)
            bucket[((size_t)b << 11) + (sub << 6) + p] =
                ((unsigned)src << 6) | (unsigned)(dst & 63);
    } else if (t < T_CONV + T_EDGE + T_W) {
        int t2 = t - (T_CONV + T_EDGE);
        if (t2 < 128 * 256) {
            int c = t2 >> 8, k = t2 & 255;
            float v = (k < 128) ? W1l[k * 128 + c] : W1r[(k - 128) * 128 + c];
            W1T[c * 256 + k] = f2bf(v);
        } else {
            int t3 = t2 - 128 * 256;            // 0..16383
            int c = t3 >> 7, k = t3 & 127;
            float v = (c < 64) ? W2l[k * 64 + c] : W2r[k * 64 + (c - 64)];
            W2T2[c * 128 + k] = f2bf(v);
        }
    } else if (t < T_TOTAL) {
        int c = t - (T_CONV + T_EDGE + T_W);
        float sc = gamma[c] * rsqrtf(var[c] + BN_EPS);
        scale_[c] = sc;
        shift_[c] = sc * (b1[c] - mean[c]) + beta[c];
    }
}

// ===========================================================================
// build_ell: one block per bucket. 32 sub-buckets -> LDS per-node lists ->
// coalesced global ell[node][64] (ushort) + deg[node].
// ===========================================================================
__global__ __launch_bounds__(256) void build_ell_kernel(
    const unsigned* __restrict__ bucket, const int* __restrict__ bcnt,
    ushort* __restrict__ ell, int* __restrict__ deg) {
    __shared__ ushort lell[64 * ELL_MAX];   // 8 KB
    __shared__ int lcnt[64];
    __shared__ int scnt[NSUB];
    const int tid = threadIdx.x;
    const int bkt = blockIdx.x;
    const int row0 = bkt << 6;

    if (tid < 64) lcnt[tid] = 0;
    else if (tid < 64 + NSUB) {
        int v = bcnt[(bkt << 5) + (tid - 64)];
        scnt[tid - 64] = v > SUBCAP ? SUBCAP : v;
    }
    __syncthreads();
    for (int i = tid; i < NSUB * SUBCAP; i += 256) {
        int s = i >> 6, q = i & 63;
        if (q < scnt[s]) {
            unsigned u = bucket[((size_t)bkt << 11) + i];
            int dl = u & 63;
            int p = atomicAdd(&lcnt[dl], 1);
            if (p < ELL_MAX) lell[(dl << 6) + p] = (ushort)(u >> 6);
        }
    }
    __syncthreads();
    if (tid < 64) {
        int node = row0 + tid;
        if (node < N_NODES) deg[node] = lcnt[tid];
    }
    const uint4* srcp = (const uint4*)lell;
    uint4* dstp = (uint4*)(ell + ((size_t)row0 << 6));
    #pragma unroll
    for (int i = 0; i < 2; ++i) dstp[i * 256 + tid] = srcp[i * 256 + tid];
}

// ===========================================================================
// gather1: Agg[n] = bf16(mean_j Xb[ell[n][j]]).  3125 blocks x 256 thr =
// 12500 waves (full-chip residency). 16 lanes per node (lane = 8ch = 16B),
// 16 nodes per block, 8 feature loads in flight per lane.
// ===========================================================================
__global__ __launch_bounds__(256) void gather1_kernel(
    const ushort* __restrict__ Xb, const ushort* __restrict__ ell,
    const int* __restrict__ deg, ushort* __restrict__ Agg) {
    const int tid = threadIdx.x;
    const int grp = tid >> 4, lane16 = tid & 15;
    const int node = blockIdx.x * 16 + grp;
    if (node >= N_NODES) return;
    const int dg = deg[node];
    const int end = dg < ELL_MAX ? dg : ELL_MAX;
    const ushort* Lp = ell + ((size_t)node << 6);
    float a0 = 0.f, a1 = 0.f, a2 = 0.f, a3 = 0.f;
    float a4 = 0.f, a5 = 0.f, a6 = 0.f, a7 = 0.f;
    int j = 0;
    for (; j + 8 <= end; j += 8) {
        ushort4 sa = *(const ushort4*)(Lp + j);
        ushort4 sb = *(const ushort4*)(Lp + j + 4);
        uint4 u0 = *(const uint4*)(Xb + ((size_t)sa.x << 7) + lane16 * 8);
        uint4 u1 = *(const uint4*)(Xb + ((size_t)sa.y << 7) + lane16 * 8);
        uint4 u2 = *(const uint4*)(Xb + ((size_t)sa.z << 7) + lane16 * 8);
        uint4 u3 = *(const uint4*)(Xb + ((size_t)sa.w << 7) + lane16 * 8);
        uint4 u4 = *(const uint4*)(Xb + ((size_t)sb.x << 7) + lane16 * 8);
        uint4 u5 = *(const uint4*)(Xb + ((size_t)sb.y << 7) + lane16 * 8);
        uint4 u6 = *(const uint4*)(Xb + ((size_t)sb.z << 7) + lane16 * 8);
        uint4 u7 = *(const uint4*)(Xb + ((size_t)sb.w << 7) + lane16 * 8);
        a0 += bf_lo(u0.x) + bf_lo(u1.x) + bf_lo(u2.x) + bf_lo(u3.x)
            + bf_lo(u4.x) + bf_lo(u5.x) + bf_lo(u6.x) + bf_lo(u7.x);
        a1 += bf_hi(u0.x) + bf_hi(u1.x) + bf_hi(u2.x) + bf_hi(u3.x)
            + bf_hi(u4.x) + bf_hi(u5.x) + bf_hi(u6.x) + bf_hi(u7.x);
        a2 += bf_lo(u0.y) + bf_lo(u1.y) + bf_lo(u2.y) + bf_lo(u3.y)
            + bf_lo(u4.y) + bf_lo(u5.y) + bf_lo(u6.y) + bf_lo(u7.y);
        a3 += bf_hi(u0.y) + bf_hi(u1.y) + bf_hi(u2.y) + bf_hi(u3.y)
            + bf_hi(u4.y) + bf_hi(u5.y) + bf_hi(u6.y) + bf_hi(u7.y);
        a4 += bf_lo(u0.z) + bf_lo(u1.z) + bf_lo(u2.z) + bf_lo(u3.z)
            + bf_lo(u4.z) + bf_lo(u5.z) + bf_lo(u6.z) + bf_lo(u7.z);
        a5 += bf_hi(u0.z) + bf_hi(u1.z) + bf_hi(u2.z) + bf_hi(u3.z)
            + bf_hi(u4.z) + bf_hi(u5.z) + bf_hi(u6.z) + bf_hi(u7.z);
        a6 += bf_lo(u0.w) + bf_lo(u1.w) + bf_lo(u2.w) + bf_lo(u3.w)
            + bf_lo(u4.w) + bf_lo(u5.w) + bf_lo(u6.w) + bf_lo(u7.w);
        a7 += bf_hi(u0.w) + bf_hi(u1.w) + bf_hi(u2.w) + bf_hi(u3.w)
            + bf_hi(u4.w) + bf_hi(u5.w) + bf_hi(u6.w) + bf_hi(u7.w);
    }
    for (; j + 4 <= end; j += 4) {
        ushort4 sa = *(const ushort4*)(Lp + j);
        uint4 u0 = *(const uint4*)(Xb + ((size_t)sa.x << 7) + lane16 * 8);
        uint4 u1 = *(const uint4*)(Xb + ((size_t)sa.y << 7) + lane16 * 8);
        uint4 u2 = *(const uint4*)(Xb + ((size_t)sa.z << 7) + lane16 * 8);
        uint4 u3 = *(const uint4*)(Xb + ((size_t)sa.w << 7) + lane16 * 8);
        a0 += bf_lo(u0.x) + bf_lo(u1.x) + bf_lo(u2.x) + bf_lo(u3.x);
        a1 += bf_hi(u0.x) + bf_hi(u1.x) + bf_hi(u2.x) + bf_hi(u3.x);
        a2 += bf_lo(u0.y) + bf_lo(u1.y) + bf_lo(u2.y) + bf_lo(u3.y);
        a3 += bf_hi(u0.y) + bf_hi(u1.y) + bf_hi(u2.y) + bf_hi(u3.y);
        a4 += bf_lo(u0.z) + bf_lo(u1.z) + bf_lo(u2.z) + bf_lo(u3.z);
        a5 += bf_hi(u0.z) + bf_hi(u1.z) + bf_hi(u2.z) + bf_hi(u3.z);
        a6 += bf_lo(u0.w) + bf_lo(u1.w) + bf_lo(u2.w) + bf_lo(u3.w);
        a7 += bf_hi(u0.w) + bf_hi(u1.w) + bf_hi(u2.w) + bf_hi(u3.w);
    }
    for (; j < end; ++j) {
        int s = Lp[j];
        uint4 u = *(const uint4*)(Xb + ((size_t)s << 7) + lane16 * 8);
        a0 += bf_lo(u.x); a1 += bf_hi(u.x);
        a2 += bf_lo(u.y); a3 += bf_hi(u.y);
        a4 += bf_lo(u.z); a5 += bf_hi(u.z);
        a6 += bf_lo(u.w); a7 += bf_hi(u.w);
    }
    float ic = 1.0f / fmaxf((float)dg, 1.0f);
    uint4 o;
    o.x = (unsigned)f2bf(a0 * ic) | ((unsigned)f2bf(a1 * ic) << 16);
    o.y = (unsigned)f2bf(a2 * ic) | ((unsigned)f2bf(a3 * ic) << 16);
    o.z = (unsigned)f2bf(a4 * ic) | ((unsigned)f2bf(a5 * ic) << 16);
    o.w = (unsigned)f2bf(a6 * ic) | ((unsigned)f2bf(a7 * ic) << 16);
    *(uint4*)(Agg + ((size_t)node << 7) + lane16 * 8) = o;
}

// ===========================================================================
// mm: per 64-row tile (256 thr = 4 waves): coalesced stage [Agg|Xb] -> sA
// (swizzled), MFMA1 -> bn+relu -> sH, MFMA2 -> Q (bf16) / R (fp32 + b2).
// Pure BW/MFMA kernel, no gather.
// ===========================================================================
__global__ __launch_bounds__(256) void mm_kernel(
    const ushort* __restrict__ Agg, const ushort* __restrict__ Xb,
    const ushort* __restrict__ W1T, const ushort* __restrict__ W2T2,
    const float* __restrict__ scale_, const float* __restrict__ shift_,
    const float* __restrict__ b2,
    ushort* __restrict__ Q, float* __restrict__ R) {
    __shared__ unsigned sAd[64 * 32 * 4];   // 32 KB
    const int tid = threadIdx.x;
    const int row0 = blockIdx.x * 64;

    // stage: 2048 granules; gx<16 <- Agg (K 0..127), else <- Xb (K 128..255)
    #pragma unroll
    for (int i = 0; i < 8; ++i) {
        int g = i * 256 + tid;
        int r = g >> 5, gx = g & 31;
        int row = row0 + r;
        uint4 v = make_uint4(0, 0, 0, 0);
        if (row < N_NODES) {
            const ushort* src = (gx < 16)
                ? (Agg + ((size_t)row << 7) + gx * 8)
                : (Xb + ((size_t)row << 7) + (gx - 16) * 8);
            v = *(const uint4*)src;
        }
        *(uint4*)&sAd[((r << 5) + (gx ^ (r & 7))) << 2] = v;
    }
    __syncthreads();

    const bf16x8* sA8 = (const bf16x8*)sAd;
    const int w = tid >> 6, l = tid & 63;
    const int wr = (w >> 1) * 32;
    const int wc = (w & 1) * 64;
    const int lr = l & 15, lk = l >> 4;

    f32x4 acc[2][4];
    #pragma unroll
    for (int mi = 0; mi < 2; ++mi)
        #pragma unroll
        for (int ni = 0; ni < 4; ++ni) acc[mi][ni] = (f32x4){0.f, 0.f, 0.f, 0.f};

    #pragma unroll
    for (int kk = 0; kk < 8; ++kk) {
        bf16x8 a[2], b[4];
        #pragma unroll
        for (int mi = 0; mi < 2; ++mi) {
            int r = wr + mi * 16 + lr;
            a[mi] = sA8[(r << 5) + ((kk * 4 + lk) ^ (r & 7))];
        }
        #pragma unroll
        for (int ni = 0; ni < 4; ++ni) {
            int c = wc + ni * 16 + lr;
            b[ni] = *(const bf16x8*)(W1T + (size_t)c * 256 + kk * 32 + lk * 8);
        }
        #pragma unroll
        for (int mi = 0; mi < 2; ++mi)
            #pragma unroll
            for (int ni = 0; ni < 4; ++ni)
                acc[mi][ni] = __builtin_amdgcn_mfma_f32_16x16x32_bf16(
                    b[ni], a[mi], acc[mi][ni], 0, 0, 0);
    }
    __syncthreads();   // all sA reads done before H overwrites low 16KB

    // bn+relu, H (bf16) -> sH = sAd[0..16KB), [64 r][16 g] swizzled
    #pragma unroll
    for (int ni = 0; ni < 4; ++ni) {
        int c0 = wc + ni * 16 + lk * 4;
        float4 sc = *(const float4*)(scale_ + c0);
        float4 sh = *(const float4*)(shift_ + c0);
        int g = c0 >> 3;
        int sub = (c0 & 4) ? 8 : 0;
        #pragma unroll
        for (int mi = 0; mi < 2; ++mi) {
            int r = wr + mi * 16 + lr;
            float h0 = fmaxf(acc[mi][ni][0] * sc.x + sh.x, 0.f);
            float h1 = fmaxf(acc[mi][ni][1] * sc.y + sh.y, 0.f);
            float h2 = fmaxf(acc[mi][ni][2] * sc.z + sh.z, 0.f);
            float h3 = fmaxf(acc[mi][ni][3] * sc.w + sh.w, 0.f);
            uint2 o;
            o.x = (unsigned)f2bf(h0) | ((unsigned)f2bf(h1) << 16);
            o.y = (unsigned)f2bf(h2) | ((unsigned)f2bf(h3) << 16);
            *(uint2*)((char*)sAd + (((r << 4) + (g ^ (r & 7))) << 4) + sub) = o;
        }
    }
    __syncthreads();

    // MFMA2: [Q|R] = H @ W2T2^T  (wave w owns rows w*16..+15)
    f32x4 acc2[8];
    #pragma unroll
    for (int ni = 0; ni < 8; ++ni) acc2[ni] = (f32x4){0.f, 0.f, 0.f, 0.f};

    const int r2 = w * 16 + lr;
    #pragma unroll
    for (int kk = 0; kk < 4; ++kk) {
        bf16x8 a = *(const bf16x8*)((const char*)sAd +
                                    (((r2 << 4) + ((kk * 4 + lk) ^ (r2 & 7))) << 4));
        #pragma unroll
        for (int ni = 0; ni < 8; ++ni) {
            const bf16x8 b = *(const bf16x8*)(W2T2 + (size_t)(ni * 16 + lr) * 128 +
                                              kk * 32 + lk * 8);
            acc2[ni] = __builtin_amdgcn_mfma_f32_16x16x32_bf16(b, a, acc2[ni], 0, 0, 0);
        }
    }

    const int rowo = row0 + r2;
    if (rowo < N_NODES) {
        #pragma unroll
        for (int ni = 0; ni < 4; ++ni) {
            int c0 = ni * 16 + lk * 4;
            ushort4 o;
            o.x = f2bf(acc2[ni][0]); o.y = f2bf(acc2[ni][1]);
            o.z = f2bf(acc2[ni][2]); o.w = f2bf(acc2[ni][3]);
            *(ushort4*)(Q + ((size_t)rowo << 6) + c0) = o;
        }
        #pragma unroll
        for (int ni = 4; ni < 8; ++ni) {
            int c0 = (ni - 4) * 16 + lk * 4;
            float4 bias = *(const float4*)(b2 + c0);
            float4 o;
            o.x = acc2[ni][0] + bias.x; o.y = acc2[ni][1] + bias.y;
            o.z = acc2[ni][2] + bias.z; o.w = acc2[ni][3] + bias.w;
            *(float4*)(R + ((size_t)rowo << 6) + c0) = o;
        }
    }
}

// ===========================================================================
// finish: out[n] = mean_j Q[j] + R[n].  3125 blocks x 256 thr, 16 nodes/block,
// 16 lanes per node (4 ch each).  Q is 6.4MB (L2/L3-hot).
// ===========================================================================
__global__ __launch_bounds__(256) void finish_kernel(
    const ushort* __restrict__ Q, const float* __restrict__ R,
    const ushort* __restrict__ ell, const int* __restrict__ deg,
    float* __restrict__ out) {
    const int tid = threadIdx.x;
    const int grp = tid >> 4, lane16 = tid & 15;
    const int node = blockIdx.x * 16 + grp;
    if (node >= N_NODES) return;
    const int dg = deg[node];
    const int end = dg < ELL_MAX ? dg : ELL_MAX;
    const ushort* Lp = ell + ((size_t)node << 6);
    float a0 = 0.f, a1 = 0.f, a2 = 0.f, a3 = 0.f;
    int j = 0;
    for (; j + 8 <= end; j += 8) {
        ushort4 sa = *(const ushort4*)(Lp + j);
        ushort4 sb = *(const ushort4*)(Lp + j + 4);
        uint2 u0 = *(const uint2*)(Q + ((size_t)sa.x << 6) + lane16 * 4);
        uint2 u1 = *(const uint2*)(Q + ((size_t)sa.y << 6) + lane16 * 4);
        uint2 u2 = *(const uint2*)(Q + ((size_t)sa.z << 6) + lane16 * 4);
        uint2 u3 = *(const uint2*)(Q + ((size_t)sa.w << 6) + lane16 * 4);
        uint2 u4 = *(const uint2*)(Q + ((size_t)sb.x << 6) + lane16 * 4);
        uint2 u5 = *(const uint2*)(Q + ((size_t)sb.y << 6) + lane16 * 4);
        uint2 u6 = *(const uint2*)(Q + ((size_t)sb.z << 6) + lane16 * 4);
        uint2 u7 = *(const uint2*)(Q + ((size_t)sb.w << 6) + lane16 * 4);
        a0 += bf_lo(u0.x) + bf_lo(u1.x) + bf_lo(u2.x) + bf_lo(u3.x)
            + bf_lo(u4.x) + bf_lo(u5.x) + bf_lo(u6.x) + bf_lo(u7.x);
        a1 += bf_hi(u0.x) + bf_hi(u1.x) + bf_hi(u2.x) + bf_hi(u3.x)
            + bf_hi(u4.x) + bf_hi(u5.x) + bf_hi(u6.x) + bf_hi(u7.x);
        a2 += bf_lo(u0.y) + bf_lo(u1.y) + bf_lo(u2.y) + bf_lo(u3.y)
            + bf_lo(u4.y) + bf_lo(u5.y) + bf_lo(u6.y) + bf_lo(u7.y);
        a3 += bf_hi(u0.y) + bf_hi(u1.y) + bf_hi(u2.y) + bf_hi(u3.y)
            + bf_hi(u4.y) + bf_hi(u5.y) + bf_hi(u6.y) + bf_hi(u7.y);
    }
    for (; j + 4 <= end; j += 4) {
        ushort4 ss = *(const ushort4*)(Lp + j);
        uint2 u0 = *(const uint2*)(Q + ((size_t)ss.x << 6) + lane16 * 4);
        uint2 u1 = *(const uint2*)(Q + ((size_t)ss.y << 6) + lane16 * 4);
        uint2 u2 = *(const uint2*)(Q + ((size_t)ss.z << 6) + lane16 * 4);
        uint2 u3 = *(const uint2*)(Q + ((size_t)ss.w << 6) + lane16 * 4);
        a0 += bf_lo(u0.x) + bf_lo(u1.x) + bf_lo(u2.x) + bf_lo(u3.x);
        a1 += bf_hi(u0.x) + bf_hi(u1.x) + bf_hi(u2.x) + bf_hi(u3.x);
        a2 += bf_lo(u0.y) + bf_lo(u1.y) + bf_lo(u2.y) + bf_lo(u3.y);
        a3 += bf_hi(u0.y) + bf_hi(u1.y) + bf_hi(u2.y) + bf_hi(u3.y);
    }
    for (; j < end; ++j) {
        int s = Lp[j];
        uint2 u = *(const uint2*)(Q + ((size_t)s << 6) + lane16 * 4);
        a0 += bf_lo(u.x); a1 += bf_hi(u.x);
        a2 += bf_lo(u.y); a3 += bf_hi(u.y);
    }
    float ic = 1.0f / fmaxf((float)dg, 1.0f);
    float4 r4 = *(const float4*)(R + ((size_t)node << 6) + lane16 * 4);
    float4 o;
    o.x = a0 * ic + r4.x;
    o.y = a1 * ic + r4.y;
    o.z = a2 * ic + r4.z;
    o.w = a3 * ic + r4.w;
    *(float4*)(out + ((size_t)node << 6) + lane16 * 4) = o;
}

// ---------------------------------------------------------------------------
extern "C" void kernel_launch(void* const* d_in, const int* in_sizes, int n_in,
                              void* d_out, int out_size, void* d_ws, size_t ws_size,
                              hipStream_t stream) {
    const float* x     = (const float*)d_in[0];
    const int*   eidx  = (const int*)d_in[1];
    const float* W1_l  = (const float*)d_in[2];
    const float* W1_r  = (const float*)d_in[3];
    const float* b1    = (const float*)d_in[4];
    const float* gamma = (const float*)d_in[5];
    const float* beta  = (const float*)d_in[6];
    const float* mean  = (const float*)d_in[7];
    const float* var   = (const float*)d_in[8];
    const float* W2_l  = (const float*)d_in[9];
    const float* W2_r  = (const float*)d_in[10];
    const float* b2    = (const float*)d_in[11];
    float* out = (float*)d_out;

    char* p = (char*)d_ws;
    ushort* Xb   = (ushort*)p; p += (size_t)N_NODES * 128 * 2;            // 12.8 MB
    ushort* Agg  = (ushort*)p; p += (size_t)N_NODES * 128 * 2;            // 12.8 MB
    ushort* Q    = (ushort*)p; p += (size_t)N_NODES * 64 * 2;             //  6.4 MB
    float*  R    = (float*)p;  p += (size_t)N_NODES * 64 * 4;             // 12.8 MB
    ushort* W1T  = (ushort*)p; p += 128 * 256 * 2;
    ushort* W2T2 = (ushort*)p; p += 128 * 128 * 2;
    float* scale_ = (float*)p; p += 128 * 4;
    float* shift_ = (float*)p; p += 128 * 4;
    unsigned* bucket = (unsigned*)p; p += (size_t)N_BUCKETS * NSUB * SUBCAP * 4; // 6.4 MB
    int* bcnt    = (int*)p;    p += (size_t)N_BUCKETS * NSUB * 4;         // 100 KB
    ushort* ell  = (ushort*)p; p += (size_t)N_BUCKETS * 64 * ELL_MAX * 2; //  6.4 MB
    int* deg     = (int*)p;    p += (size_t)N_NODES * 4;                  // 200 KB

    hipMemsetAsync(bcnt, 0, (size_t)N_BUCKETS * NSUB * sizeof(int), stream);

    prep_scatter_kernel<<<(T_TOTAL + 255) / 256, 256, 0, stream>>>(
        x, eidx, W1_l, W1_r, W2_l, W2_r, gamma, beta, mean, var, b1,
        Xb, W1T, W2T2, scale_, shift_, bcnt, bucket);

    build_ell_kernel<<<N_BUCKETS, 256, 0, stream>>>(bucket, bcnt, ell, deg);

    gather1_kernel<<<(N_NODES + 15) / 16, 256, 0, stream>>>(Xb, ell, deg, Agg);

    mm_kernel<<<N_BUCKETS, 256, 0, stream>>>(
        Agg, Xb, W1T, W2T2, scale_, shift_, b2, Q, R);

    finish_kernel<<<(N_NODES + 15) / 16, 256, 0, stream>>>(Q, R, ell, deg, out);
}

// Round 7
// 118.337 us; speedup vs baseline: 1.2156x; 1.1310x over previous
//
#include <hip/hip_runtime.h>
#include <hip/hip_bf16.h>

#define N_NODES 50000
#define N_EDGES 600000
#define BN_EPS 1e-5f
#define ELL_MAX 64          // per-node list cap; P(deg>=64) ~ 1e-30
#define N_BUCKETS 782       // ceil(50000/64) 64-node tiles
#define BUCKET_CAP 1024     // lambda=768, sigma=27.7 -> +9.2 sigma

#define EPT 32              // edges per thread in the binning blocks
#define EB_EDGES (256 * EPT)                    // 8192
#define N_EB ((N_EDGES + EB_EDGES - 1) / EB_EDGES)   // 74
#define N_CONV_BLK 6250                         // 1.6M threads / 256
#define N_W_BLK 192                             // 49152 / 256
#define PREP_GRID (N_EB + N_CONV_BLK + N_W_BLK + 1)

typedef short bf16x8 __attribute__((ext_vector_type(8)));
typedef float f32x4 __attribute__((ext_vector_type(4)));

__device__ __forceinline__ ushort f2bf(float f) {
    unsigned u = __float_as_uint(f);
    u += 0x7fffu + ((u >> 16) & 1u);
    return (ushort)(u >> 16);
}
__device__ __forceinline__ float bf_lo(unsigned u) { return __uint_as_float(u << 16); }
__device__ __forceinline__ float bf_hi(unsigned u) { return __uint_as_float(u & 0xffff0000u); }

// ===========================================================================
// prep_scatter (block-range partitioned):
//   blocks [0, N_EB): LDS-aggregated edge binning.
//     E1: LDS histogram over 782 buckets; LDS-atomic return = local rank.
//     E2: ONE global atomicAdd per non-empty bin per block (58k total, was
//         600k) -> base slot.
//     E3: scatter (src<<6)|(dst&63) at bucket[b][base+rank] -- same-bin
//         entries write consecutive addresses.
//   blocks [N_EB, +6250): x -> bf16 (Xb), coalesced float4.
//   blocks [.., +192): weight transpose W1T / W2T2.
//   last block: bn fold.
// Edge blocks FIRST so their atomic latency hides under the conv stream.
// ===========================================================================
__global__ __launch_bounds__(256) void prep_scatter_kernel(
    const float* __restrict__ x, const int* __restrict__ eidx,
    const float* __restrict__ W1l, const float* __restrict__ W1r,
    const float* __restrict__ W2l, const float* __restrict__ W2r,
    const float* __restrict__ gamma, const float* __restrict__ beta,
    const float* __restrict__ mean, const float* __restrict__ var,
    const float* __restrict__ b1,
    ushort* __restrict__ Xb, ushort* __restrict__ W1T, ushort* __restrict__ W2T2,
    float* __restrict__ scale_, float* __restrict__ shift_,
    int* __restrict__ bcnt, unsigned* __restrict__ bucket) {
    const int blk = blockIdx.x;
    const int tid = threadIdx.x;

    if (blk < N_EB) {
        __shared__ int lcnt[N_BUCKETS];
        __shared__ int lbase[N_BUCKETS];
        const int e0 = blk * EB_EDGES;
        const int n = (N_EDGES - e0) < EB_EDGES ? (N_EDGES - e0) : EB_EDGES;

        for (int i = tid; i < N_BUCKETS; i += 256) lcnt[i] = 0;
        __syncthreads();

        // E1: histogram + rank.  pk = (b<<19)|(rank<<6)|dstlo  (sentinel ~0)
        unsigned pk[EPT];
        ushort2 sp[EPT / 2];
        #pragma unroll
        for (int i = 0; i < EPT; ++i) {
            int e = e0 + i * 256 + tid;
            if (i * 256 + tid < n) {
                int src = eidx[e];
                int dst = eidx[N_EDGES + e];
                int b = dst >> 6;
                int r = atomicAdd(&lcnt[b], 1);
                pk[i] = ((unsigned)b << 19) | ((unsigned)r << 6) | (unsigned)(dst & 63);
                if (i & 1) sp[i >> 1].y = (ushort)src; else sp[i >> 1].x = (ushort)src;
            } else {
                pk[i] = 0xFFFFFFFFu;
            }
        }
        __syncthreads();

        // E2: one global atomic per non-empty bin
        for (int i = tid; i < N_BUCKETS; i += 256) {
            int c = lcnt[i];
            lbase[i] = c ? atomicAdd(&bcnt[i], c) : 0;
        }
        __syncthreads();

        // E3: grouped scatter
        #pragma unroll
        for (int i = 0; i < EPT; ++i) {
            if (pk[i] != 0xFFFFFFFFu) {
                int b = pk[i] >> 19;
                int r = (pk[i] >> 6) & 0x1FFF;
                int dl = pk[i] & 63;
                unsigned src = (i & 1) ? sp[i >> 1].y : sp[i >> 1].x;
                int p = lbase[b] + r;
                if (p < BUCKET_CAP)
                    bucket[(size_t)b * BUCKET_CAP + p] = (src << 6) | (unsigned)dl;
            }
        }
    } else if (blk < N_EB + N_CONV_BLK) {
        int t = (blk - N_EB) * 256 + tid;           // < 1,600,000
        int row = t >> 5, c4 = t & 31;
        float4 v = *(const float4*)(x + (size_t)row * 128 + c4 * 4);
        ushort4 o;
        o.x = f2bf(v.x); o.y = f2bf(v.y); o.z = f2bf(v.z); o.w = f2bf(v.w);
        *(ushort4*)(Xb + (size_t)row * 128 + c4 * 4) = o;
    } else if (blk < N_EB + N_CONV_BLK + N_W_BLK) {
        int t2 = (blk - N_EB - N_CONV_BLK) * 256 + tid;   // < 49152
        if (t2 < 128 * 256) {
            int c = t2 >> 8, k = t2 & 255;
            float v = (k < 128) ? W1l[k * 128 + c] : W1r[(k - 128) * 128 + c];
            W1T[c * 256 + k] = f2bf(v);
        } else {
            int t3 = t2 - 128 * 256;            // 0..16383
            int c = t3 >> 7, k = t3 & 127;
            float v = (c < 64) ? W2l[k * 64 + c] : W2r[k * 64 + (c - 64)];
            W2T2[c * 128 + k] = f2bf(v);
        }
    } else {
        if (tid < 128) {
            int c = tid;
            float sc = gamma[c] * rsqrtf(var[c] + BN_EPS);
            scale_[c] = sc;
            shift_[c] = sc * (b1[c] - mean[c]) + beta[c];
        }
    }
}

// ===========================================================================
// build_ell: one block per bucket. Contiguous bucket list -> LDS per-node
// lists -> coalesced global ell[node][64] (ushort) + deg[node].
// ===========================================================================
__global__ __launch_bounds__(256) void build_ell_kernel(
    const unsigned* __restrict__ bucket, const int* __restrict__ bcnt,
    ushort* __restrict__ ell, int* __restrict__ deg) {
    __shared__ ushort lell[64 * ELL_MAX];   // 8 KB
    __shared__ int lcnt[64];
    const int tid = threadIdx.x;
    const int bkt = blockIdx.x;
    const int row0 = bkt << 6;

    if (tid < 64) lcnt[tid] = 0;
    int n = bcnt[bkt];
    if (n > BUCKET_CAP) n = BUCKET_CAP;
    __syncthreads();
    for (int i = tid; i < n; i += 256) {
        unsigned u = bucket[(size_t)bkt * BUCKET_CAP + i];
        int dl = u & 63;
        int p = atomicAdd(&lcnt[dl], 1);
        if (p < ELL_MAX) lell[(dl << 6) + p] = (ushort)(u >> 6);
    }
    __syncthreads();
    if (tid < 64) {
        int node = row0 + tid;
        if (node < N_NODES) deg[node] = lcnt[tid];
    }
    const uint4* srcp = (const uint4*)lell;
    uint4* dstp = (uint4*)(ell + ((size_t)row0 << 6));
    #pragma unroll
    for (int i = 0; i < 2; ++i) dstp[i * 256 + tid] = srcp[i * 256 + tid];
}

// ===========================================================================
// gather1: Agg[n] = bf16(mean_j Xb[ell[n][j]]).  3125 blocks x 256 thr =
// 12500 waves (full-chip residency). 16 lanes per node (lane = 8ch = 16B).
// ===========================================================================
__global__ __launch_bounds__(256) void gather1_kernel(
    const ushort* __restrict__ Xb, const ushort* __restrict__ ell,
    const int* __restrict__ deg, ushort* __restrict__ Agg) {
    const int tid = threadIdx.x;
    const int grp = tid >> 4, lane16 = tid & 15;
    const int node = blockIdx.x * 16 + grp;
    if (node >= N_NODES) return;
    const int dg = deg[node];
    const int end = dg < ELL_MAX ? dg : ELL_MAX;
    const ushort* Lp = ell + ((size_t)node << 6);
    float a0 = 0.f, a1 = 0.f, a2 = 0.f, a3 = 0.f;
    float a4 = 0.f, a5 = 0.f, a6 = 0.f, a7 = 0.f;
    int j = 0;
    for (; j + 8 <= end; j += 8) {
        ushort4 sa = *(const ushort4*)(Lp + j);
        ushort4 sb = *(const ushort4*)(Lp + j + 4);
        uint4 u0 = *(const uint4*)(Xb + ((size_t)sa.x << 7) + lane16 * 8);
        uint4 u1 = *(const uint4*)(Xb + ((size_t)sa.y << 7) + lane16 * 8);
        uint4 u2 = *(const uint4*)(Xb + ((size_t)sa.z << 7) + lane16 * 8);
        uint4 u3 = *(const uint4*)(Xb + ((size_t)sa.w << 7) + lane16 * 8);
        uint4 u4 = *(const uint4*)(Xb + ((size_t)sb.x << 7) + lane16 * 8);
        uint4 u5 = *(const uint4*)(Xb + ((size_t)sb.y << 7) + lane16 * 8);
        uint4 u6 = *(const uint4*)(Xb + ((size_t)sb.z << 7) + lane16 * 8);
        uint4 u7 = *(const uint4*)(Xb + ((size_t)sb.w << 7) + lane16 * 8);
        a0 += bf_lo(u0.x) + bf_lo(u1.x) + bf_lo(u2.x) + bf_lo(u3.x)
            + bf_lo(u4.x) + bf_lo(u5.x) + bf_lo(u6.x) + bf_lo(u7.x);
        a1 += bf_hi(u0.x) + bf_hi(u1.x) + bf_hi(u2.x) + bf_hi(u3.x)
            + bf_hi(u4.x) + bf_hi(u5.x) + bf_hi(u6.x) + bf_hi(u7.x);
        a2 += bf_lo(u0.y) + bf_lo(u1.y) + bf_lo(u2.y) + bf_lo(u3.y)
            + bf_lo(u4.y) + bf_lo(u5.y) + bf_lo(u6.y) + bf_lo(u7.y);
        a3 += bf_hi(u0.y) + bf_hi(u1.y) + bf_hi(u2.y) + bf_hi(u3.y)
            + bf_hi(u4.y) + bf_hi(u5.y) + bf_hi(u6.y) + bf_hi(u7.y);
        a4 += bf_lo(u0.z) + bf_lo(u1.z) + bf_lo(u2.z) + bf_lo(u3.z)
            + bf_lo(u4.z) + bf_lo(u5.z) + bf_lo(u6.z) + bf_lo(u7.z);
        a5 += bf_hi(u0.z) + bf_hi(u1.z) + bf_hi(u2.z) + bf_hi(u3.z)
            + bf_hi(u4.z) + bf_hi(u5.z) + bf_hi(u6.z) + bf_hi(u7.z);
        a6 += bf_lo(u0.w) + bf_lo(u1.w) + bf_lo(u2.w) + bf_lo(u3.w)
            + bf_lo(u4.w) + bf_lo(u5.w) + bf_lo(u6.w) + bf_lo(u7.w);
        a7 += bf_hi(u0.w) + bf_hi(u1.w) + bf_hi(u2.w) + bf_hi(u3.w)
            + bf_hi(u4.w) + bf_hi(u5.w) + bf_hi(u6.w) + bf_hi(u7.w);
    }
    for (; j + 4 <= end; j += 4) {
        ushort4 sa = *(const ushort4*)(Lp + j);
        uint4 u0 = *(const uint4*)(Xb + ((size_t)sa.x << 7) + lane16 * 8);
        uint4 u1 = *(const uint4*)(Xb + ((size_t)sa.y << 7) + lane16 * 8);
        uint4 u2 = *(const uint4*)(Xb + ((size_t)sa.z << 7) + lane16 * 8);
        uint4 u3 = *(const uint4*)(Xb + ((size_t)sa.w << 7) + lane16 * 8);
        a0 += bf_lo(u0.x) + bf_lo(u1.x) + bf_lo(u2.x) + bf_lo(u3.x);
        a1 += bf_hi(u0.x) + bf_hi(u1.x) + bf_hi(u2.x) + bf_hi(u3.x);
        a2 += bf_lo(u0.y) + bf_lo(u1.y) + bf_lo(u2.y) + bf_lo(u3.y);
        a3 += bf_hi(u0.y) + bf_hi(u1.y) + bf_hi(u2.y) + bf_hi(u3.y);
        a4 += bf_lo(u0.z) + bf_lo(u1.z) + bf_lo(u2.z) + bf_lo(u3.z);
        a5 += bf_hi(u0.z) + bf_hi(u1.z) + bf_hi(u2.z) + bf_hi(u3.z);
        a6 += bf_lo(u0.w) + bf_lo(u1.w) + bf_lo(u2.w) + bf_lo(u3.w);
        a7 += bf_hi(u0.w) + bf_hi(u1.w) + bf_hi(u2.w) + bf_hi(u3.w);
    }
    for (; j < end; ++j) {
        int s = Lp[j];
        uint4 u = *(const uint4*)(Xb + ((size_t)s << 7) + lane16 * 8);
        a0 += bf_lo(u.x); a1 += bf_hi(u.x);
        a2 += bf_lo(u.y); a3 += bf_hi(u.y);
        a4 += bf_lo(u.z); a5 += bf_hi(u.z);
        a6 += bf_lo(u.w); a7 += bf_hi(u.w);
    }
    float ic = 1.0f / fmaxf((float)dg, 1.0f);
    uint4 o;
    o.x = (unsigned)f2bf(a0 * ic) | ((unsigned)f2bf(a1 * ic) << 16);
    o.y = (unsigned)f2bf(a2 * ic) | ((unsigned)f2bf(a3 * ic) << 16);
    o.z = (unsigned)f2bf(a4 * ic) | ((unsigned)f2bf(a5 * ic) << 16);
    o.w = (unsigned)f2bf(a6 * ic) | ((unsigned)f2bf(a7 * ic) << 16);
    *(uint4*)(Agg + ((size_t)node << 7) + lane16 * 8) = o;
}

// ===========================================================================
// mm: per 64-row tile (256 thr = 4 waves): coalesced stage [Agg|Xb] -> sA
// (swizzled), MFMA1 -> bn+relu -> sH, MFMA2 -> Q (bf16) / R (fp32 + b2).
// ===========================================================================
__global__ __launch_bounds__(256) void mm_kernel(
    const ushort* __restrict__ Agg, const ushort* __restrict__ Xb,
    const ushort* __restrict__ W1T, const ushort* __restrict__ W2T2,
    const float* __restrict__ scale_, const float* __restrict__ shift_,
    const float* __restrict__ b2,
    ushort* __restrict__ Q, float* __restrict__ R) {
    __shared__ unsigned sAd[64 * 32 * 4];   // 32 KB
    const int tid = threadIdx.x;
    const int row0 = blockIdx.x * 64;

    #pragma unroll
    for (int i = 0; i < 8; ++i) {
        int g = i * 256 + tid;
        int r = g >> 5, gx = g & 31;
        int row = row0 + r;
        uint4 v = make_uint4(0, 0, 0, 0);
        if (row < N_NODES) {
            const ushort* src = (gx < 16)
                ? (Agg + ((size_t)row << 7) + gx * 8)
                : (Xb + ((size_t)row << 7) + (gx - 16) * 8);
            v = *(const uint4*)src;
        }
        *(uint4*)&sAd[((r << 5) + (gx ^ (r & 7))) << 2] = v;
    }
    __syncthreads();

    const bf16x8* sA8 = (const bf16x8*)sAd;
    const int w = tid >> 6, l = tid & 63;
    const int wr = (w >> 1) * 32;
    const int wc = (w & 1) * 64;
    const int lr = l & 15, lk = l >> 4;

    f32x4 acc[2][4];
    #pragma unroll
    for (int mi = 0; mi < 2; ++mi)
        #pragma unroll
        for (int ni = 0; ni < 4; ++ni) acc[mi][ni] = (f32x4){0.f, 0.f, 0.f, 0.f};

    #pragma unroll
    for (int kk = 0; kk < 8; ++kk) {
        bf16x8 a[2], b[4];
        #pragma unroll
        for (int mi = 0; mi < 2; ++mi) {
            int r = wr + mi * 16 + lr;
            a[mi] = sA8[(r << 5) + ((kk * 4 + lk) ^ (r & 7))];
        }
        #pragma unroll
        for (int ni = 0; ni < 4; ++ni) {
            int c = wc + ni * 16 + lr;
            b[ni] = *(const bf16x8*)(W1T + (size_t)c * 256 + kk * 32 + lk * 8);
        }
        #pragma unroll
        for (int mi = 0; mi < 2; ++mi)
            #pragma unroll
            for (int ni = 0; ni < 4; ++ni)
                acc[mi][ni] = __builtin_amdgcn_mfma_f32_16x16x32_bf16(
                    b[ni], a[mi], acc[mi][ni], 0, 0, 0);
    }
    __syncthreads();

    #pragma unroll
    for (int ni = 0; ni < 4; ++ni) {
        int c0 = wc + ni * 16 + lk * 4;
        float4 sc = *(const float4*)(scale_ + c0);
        float4 sh = *(const float4*)(shift_ + c0);
        int g = c0 >> 3;
        int sub = (c0 & 4) ? 8 : 0;
        #pragma unroll
        for (int mi = 0; mi < 2; ++mi) {
            int r = wr + mi * 16 + lr;
            float h0 = fmaxf(acc[mi][ni][0] * sc.x + sh.x, 0.f);
            float h1 = fmaxf(acc[mi][ni][1] * sc.y + sh.y, 0.f);
            float h2 = fmaxf(acc[mi][ni][2] * sc.z + sh.z, 0.f);
            float h3 = fmaxf(acc[mi][ni][3] * sc.w + sh.w, 0.f);
            uint2 o;
            o.x = (unsigned)f2bf(h0) | ((unsigned)f2bf(h1) << 16);
            o.y = (unsigned)f2bf(h2) | ((unsigned)f2bf(h3) << 16);
            *(uint2*)((char*)sAd + (((r << 4) + (g ^ (r & 7))) << 4) + sub) = o;
        }
    }
    __syncthreads();

    f32x4 acc2[8];
    #pragma unroll
    for (int ni = 0; ni < 8; ++ni) acc2[ni] = (f32x4){0.f, 0.f, 0.f, 0.f};

    const int r2 = w * 16 + lr;
    #pragma unroll
    for (int kk = 0; kk < 4; ++kk) {
        bf16x8 a = *(const bf16x8*)((const char*)sAd +
                                    (((r2 << 4) + ((kk * 4 + lk) ^ (r2 & 7))) << 4));
        #pragma unroll
        for (int ni = 0; ni < 8; ++ni) {
            const bf16x8 b = *(const bf16x8*)(W2T2 + (size_t)(ni * 16 + lr) * 128 +
                                              kk * 32 + lk * 8);
            acc2[ni] = __builtin_amdgcn_mfma_f32_16x16x32_bf16(b, a, acc2[ni], 0, 0, 0);
        }
    }

    const int rowo = row0 + r2;
    if (rowo < N_NODES) {
        #pragma unroll
        for (int ni = 0; ni < 4; ++ni) {
            int c0 = ni * 16 + lk * 4;
            ushort4 o;
            o.x = f2bf(acc2[ni][0]); o.y = f2bf(acc2[ni][1]);
            o.z = f2bf(acc2[ni][2]); o.w = f2bf(acc2[ni][3]);
            *(ushort4*)(Q + ((size_t)rowo << 6) + c0) = o;
        }
        #pragma unroll
        for (int ni = 4; ni < 8; ++ni) {
            int c0 = (ni - 4) * 16 + lk * 4;
            float4 bias = *(const float4*)(b2 + c0);
            float4 o;
            o.x = acc2[ni][0] + bias.x; o.y = acc2[ni][1] + bias.y;
            o.z = acc2[ni][2] + bias.z; o.w = acc2[ni][3] + bias.w;
            *(float4*)(R + ((size_t)rowo << 6) + c0) = o;
        }
    }
}

// ===========================================================================
// finish: out[n] = mean_j Q[j] + R[n].  3125 blocks x 256 thr, 16 nodes/blk.
// ===========================================================================
__global__ __launch_bounds__(256) void finish_kernel(
    const ushort* __restrict__ Q, const float* __restrict__ R,
    const ushort* __restrict__ ell, const int* __restrict__ deg,
    float* __restrict__ out) {
    const int tid = threadIdx.x;
    const int grp = tid >> 4, lane16 = tid & 15;
    const int node = blockIdx.x * 16 + grp;
    if (node >= N_NODES) return;
    const int dg = deg[node];
    const int end = dg < ELL_MAX ? dg : ELL_MAX;
    const ushort* Lp = ell + ((size_t)node << 6);
    float a0 = 0.f, a1 = 0.f, a2 = 0.f, a3 = 0.f;
    int j = 0;
    for (; j + 8 <= end; j += 8) {
        ushort4 sa = *(const ushort4*)(Lp + j);
        ushort4 sb = *(const ushort4*)(Lp + j + 4);
        uint2 u0 = *(const uint2*)(Q + ((size_t)sa.x << 6) + lane16 * 4);
        uint2 u1 = *(const uint2*)(Q + ((size_t)sa.y << 6) + lane16 * 4);
        uint2 u2 = *(const uint2*)(Q + ((size_t)sa.z << 6) + lane16 * 4);
        uint2 u3 = *(const uint2*)(Q + ((size_t)sa.w << 6) + lane16 * 4);
        uint2 u4 = *(const uint2*)(Q + ((size_t)sb.x << 6) + lane16 * 4);
        uint2 u5 = *(const uint2*)(Q + ((size_t)sb.y << 6) + lane16 * 4);
        uint2 u6 = *(const uint2*)(Q + ((size_t)sb.z << 6) + lane16 * 4);
        uint2 u7 = *(const uint2*)(Q + ((size_t)sb.w << 6) + lane16 * 4);
        a0 += bf_lo(u0.x) + bf_lo(u1.x) + bf_lo(u2.x) + bf_lo(u3.x)
            + bf_lo(u4.x) + bf_lo(u5.x) + bf_lo(u6.x) + bf_lo(u7.x);
        a1 += bf_hi(u0.x) + bf_hi(u1.x) + bf_hi(u2.x) + bf_hi(u3.x)
            + bf_hi(u4.x) + bf_hi(u5.x) + bf_hi(u6.x) + bf_hi(u7.x);
        a2 += bf_lo(u0.y) + bf_lo(u1.y) + bf_lo(u2.y) + bf_lo(u3.y)
            + bf_lo(u4.y) + bf_lo(u5.y) + bf_lo(u6.y) + bf_lo(u7.y);
        a3 += bf_hi(u0.y) + bf_hi(u1.y) + bf_hi(u2.y) + bf_hi(u3.y)
            + bf_hi(u4.y) + bf_hi(u5.y) + bf_hi(u6.y) + bf_hi(u7.y);
    }
    for (; j + 4 <= end; j += 4) {
        ushort4 ss = *(const ushort4*)(Lp + j);
        uint2 u0 = *(const uint2*)(Q + ((size_t)ss.x << 6) + lane16 * 4);
        uint2 u1 = *(const uint2*)(Q + ((size_t)ss.y << 6) + lane16 * 4);
        uint2 u2 = *(const uint2*)(Q + ((size_t)ss.z << 6) + lane16 * 4);
        uint2 u3 = *(const uint2*)(Q + ((size_t)ss.w << 6) + lane16 * 4);
        a0 += bf_lo(u0.x) + bf_lo(u1.x) + bf_lo(u2.x) + bf_lo(u3.x);
        a1 += bf_hi(u0.x) + bf_hi(u1.x) + bf_hi(u2.x) + bf_hi(u3.x);
        a2 += bf_lo(u0.y) + bf_lo(u1.y) + bf_lo(u2.y) + bf_lo(u3.y);
        a3 += bf_hi(u0.y) + bf_hi(u1.y) + bf_hi(u2.y) + bf_hi(u3.y);
    }
    for (; j < end; ++j) {
        int s = Lp[j];
        uint2 u = *(const uint2*)(Q + ((size_t)s << 6) + lane16 * 4);
        a0 += bf_lo(u.x); a1 += bf_hi(u.x);
        a2 += bf_lo(u.y); a3 += bf_hi(u.y);
    }
    float ic = 1.0f / fmaxf((float)dg, 1.0f);
    float4 r4 = *(const float4*)(R + ((size_t)node << 6) + lane16 * 4);
    float4 o;
    o.x = a0 * ic + r4.x;
    o.y = a1 * ic + r4.y;
    o.z = a2 * ic + r4.z;
    o.w = a3 * ic + r4.w;
    *(float4*)(out + ((size_t)node << 6) + lane16 * 4) = o;
}

// ---------------------------------------------------------------------------
extern "C" void kernel_launch(void* const* d_in, const int* in_sizes, int n_in,
                              void* d_out, int out_size, void* d_ws, size_t ws_size,
                              hipStream_t stream) {
    const float* x     = (const float*)d_in[0];
    const int*   eidx  = (const int*)d_in[1];
    const float* W1_l  = (const float*)d_in[2];
    const float* W1_r  = (const float*)d_in[3];
    const float* b1    = (const float*)d_in[4];
    const float* gamma = (const float*)d_in[5];
    const float* beta  = (const float*)d_in[6];
    const float* mean  = (const float*)d_in[7];
    const float* var   = (const float*)d_in[8];
    const float* W2_l  = (const float*)d_in[9];
    const float* W2_r  = (const float*)d_in[10];
    const float* b2    = (const float*)d_in[11];
    float* out = (float*)d_out;

    char* p = (char*)d_ws;
    ushort* Xb   = (ushort*)p; p += (size_t)N_NODES * 128 * 2;            // 12.8 MB
    ushort* Agg  = (ushort*)p; p += (size_t)N_NODES * 128 * 2;            // 12.8 MB
    ushort* Q    = (ushort*)p; p += (size_t)N_NODES * 64 * 2;             //  6.4 MB
    float*  R    = (float*)p;  p += (size_t)N_NODES * 64 * 4;             // 12.8 MB
    ushort* W1T  = (ushort*)p; p += 128 * 256 * 2;
    ushort* W2T2 = (ushort*)p; p += 128 * 128 * 2;
    float* scale_ = (float*)p; p += 128 * 4;
    float* shift_ = (float*)p; p += 128 * 4;
    unsigned* bucket = (unsigned*)p; p += (size_t)N_BUCKETS * BUCKET_CAP * 4; // 3.2 MB
    int* bcnt    = (int*)p;    p += (size_t)N_BUCKETS * 4;                // 3.1 KB
    ushort* ell  = (ushort*)p; p += (size_t)N_BUCKETS * 64 * ELL_MAX * 2; //  6.4 MB
    int* deg     = (int*)p;    p += (size_t)N_NODES * 4;                  // 200 KB

    hipMemsetAsync(bcnt, 0, (size_t)N_BUCKETS * sizeof(int), stream);

    prep_scatter_kernel<<<PREP_GRID, 256, 0, stream>>>(
        x, eidx, W1_l, W1_r, W2_l, W2_r, gamma, beta, mean, var, b1,
        Xb, W1T, W2T2, scale_, shift_, bcnt, bucket);

    build_ell_kernel<<<N_BUCKETS, 256, 0, stream>>>(bucket, bcnt, ell, deg);

    gather1_kernel<<<(N_NODES + 15) / 16, 256, 0, stream>>>(Xb, ell, deg, Agg);

    mm_kernel<<<N_BUCKETS, 256, 0, stream>>>(
        Agg, Xb, W1T, W2T2, scale_, shift_, b2, Q, R);

    finish_kernel<<<(N_NODES + 15) / 16, 256, 0, stream>>>(Q, R, ell, deg, out);
}